// Round 7
// baseline (119.853 us; speedup 1.0000x reference)
//
#include <hip/hip_runtime.h>
#include <hip/hip_bf16.h>

// STDP via the antisymmetric-kernel identity (verified R6, absmax 9.8e-4):
//   out[q,p] = 4w(1-w) * A_SCALE * sum_{b,t} post_s[b,t,q] * Z[b,t,p]
//   Z = pre_tr - pre_rt;  tr = causal decay scan, rt = anti-causal scan.
//   AT[q][b*128+t] = post_spikes (bf16);  BT[p][b*128+t] = Z (bf16)

typedef __attribute__((ext_vector_type(8))) short bf16x8;
typedef __attribute__((ext_vector_type(4))) float f32x4;

#define GN 2048
#define KTOT 2048
#define A_SCALE (0.01f / 16.0f)
#define FST 68   // fbuf dword stride (16B-aligned float4 rows)
#define ZST 66   // zbuf elem stride (8B-aligned packed writes)

#define GLOAD_LDS16(gp, lp) \
    __builtin_amdgcn_global_load_lds((const __attribute__((address_space(1))) void*)(gp), \
                                     (__attribute__((address_space(3))) void*)(lp), 16, 0, 0)

__device__ __forceinline__ unsigned bf16bits(float x) {
    __hip_bfloat16 h = __float2bfloat16(x);
    return (unsigned)*(unsigned short*)&h;
}

// ---------------------------------------------------------------------------
// Kernel 1: transpose (+ double scan for the pre side), float4 global loads.
// grid (32, 16, 2), block 256 (4 waves). z=0: post -> AT, z=1: pre -> BT.
// zbuf overlays fbuf.  LDS 34816 B -> 4 blocks/CU.  (~12 us, near HBM floor)
// UNCHANGED from the proven baseline.
// ---------------------------------------------------------------------------
__global__ __launch_bounds__(256, 4) void trace_kernel(
    const float* __restrict__ pre,
    const float* __restrict__ post,
    const int* __restrict__ dtp,
    __hip_bfloat16* __restrict__ AT,
    __hip_bfloat16* __restrict__ BT)
{
    __shared__ float fbuf[128 * FST];                    // 34816 B, t-major fp32
    __hip_bfloat16* zbuf = (__hip_bfloat16*)fbuf;        // overlay, t-major bf16

    const int tid = threadIdx.x;
    const int w   = tid >> 6;    // wave 0..3
    const int l   = tid & 63;
    const int nq  = tid & 15;    // float4 group along n
    const int tl  = tid >> 4;    // t-row within a 16-row pass
    const int n0  = blockIdx.x * 64;
    const int b   = blockIdx.y;
    const int a   = blockIdx.z;  // 0: post->AT, 1: pre->BT

    int di = dtp[0];
    float dtf = (di > 0 && di < 1000000) ? (float)di : *(const float*)dtp;
    const float decay = __expf(-dtf / 20.0f);

    if (a == 0) {
        #pragma unroll
        for (int pass = 0; pass < 8; ++pass) {
            const int t = pass * 16 + tl;
            float4 v = *(const float4*)&post[((size_t)b * 128 + t) * GN + n0 + 4 * nq];
            uint2 pk;
            pk.x = bf16bits(v.x) | (bf16bits(v.y) << 16);
            pk.y = bf16bits(v.z) | (bf16bits(v.w) << 16);
            *(uint2*)&zbuf[t * ZST + 4 * nq] = pk;
        }
        __syncthreads();
    } else {
        #pragma unroll
        for (int pass = 0; pass < 8; ++pass) {
            const int t = pass * 16 + tl;
            float4 v = *(const float4*)&pre[((size_t)b * 128 + t) * GN + n0 + 4 * nq];
            *(float4*)&fbuf[t * FST + 4 * nq] = v;
        }
        __syncthreads();

        const int t0 = 32 * w;   // this wave's t segment [t0, t0+32)
        float carry = 0.0f;
        #pragma unroll 8
        for (int t = 1; t < t0; ++t)
            carry = decay * carry + fbuf[t * FST + l];
        float z[32];
        #pragma unroll
        for (int j = 0; j < 32; ++j) {
            const int t = t0 + j;
            if (t >= 1) carry = decay * carry + fbuf[t * FST + l];
            z[j] = carry;                     // tr (t=0 -> 0)
        }
        float bc = 0.0f;
        #pragma unroll 8
        for (int t = 127; t >= t0 + 32; --t)
            bc = decay * bc + fbuf[t * FST + l];
        #pragma unroll
        for (int j = 31; j >= 0; --j) {
            const int t = t0 + j;
            bc = decay * bc + fbuf[t * FST + l];
            if (t >= 1) z[j] -= bc;           // Z = tr - rt   (Z[0] = 0)
        }
        __syncthreads();   // all waves done reading fbuf before zbuf overlay
        #pragma unroll
        for (int j = 0; j < 32; ++j)
            zbuf[(t0 + j) * ZST + l] = __float2bfloat16(z[j]);
        __syncthreads();
    }

    __hip_bfloat16* dst = (a == 0) ? AT : BT;
    #pragma unroll
    for (int j = 0; j < 4; ++j) {
        const int c  = tid + 256 * j;   // 0..1023
        const int n  = c >> 4;          // 0..63
        const int tc = c & 15;          // 8-t chunk
        unsigned int vv[8];
        #pragma unroll
        for (int i = 0; i < 8; ++i)
            vv[i] = *(const unsigned short*)&zbuf[(8 * tc + i) * ZST + n];
        uint4 pk;
        pk.x = vv[0] | (vv[1] << 16);
        pk.y = vv[2] | (vv[3] << 16);
        pk.z = vv[4] | (vv[5] << 16);
        pk.w = vv[6] | (vv[7] << 16);
        *(uint4*)(dst + (size_t)(n0 + n) * KTOT + b * 128 + tc * 8) = pk;
    }
}

// ---------------------------------------------------------------------------
// Kernel 2: out = 4w(1-w)*A_SCALE * (AT * BT^T).
// R7 = R6 pipeline (117.7us best) with HIGHER FRAGMENT REUSE:
// wave tile 32x32 -> 64x32 (m_rep=4, n_rep=2), so 12 ds_read_b128 feed
// 16 MFMAs (0.75 KB/MFMA vs R6's 1.0).  R6 post-mortem: gemm ~31us of
// which ~20.5us is LDS read ISSUE (128 b128-inst/step/CU x 12cyc x 32
// steps).  This cuts read-inst/step/CU to 96 (-25%) -> ~15.4us.
// Geometry: same 512 blocks x 128x64 tile, but 256 threads = 4 waves in a
// 2x2 grid of 64x32 wave tiles -- EXACTLY the 122us baseline's proven wave
// geometry (wm in {0,64}, wn in {0,32}, 16-row/quad-slot reads, measured
// 0 bank conflicts), transplanted into the proven R4/R6 counted-vmcnt
// 3-buffer pipeline.  LDS 3 x 24KB = 72KB -> 2 blocks/CU, 8 waves/CU
// (2/SIMD -- NOT R5's fatal 1/SIMD).
// Staging: 1536 chunks / 256 lanes = 6 gload_lds per lane per tile ->
// steady-state wait is vmcnt(6) (tile h+2 in flight, h+1 landed; same
// induction proof as R4/R6).  Drain-0 only at the tail.  Uniform barriers;
// sched_barrier(0) after each (rule #18).  8-slot XOR swizzle on 128B rows.
// K-order: kk ascending -> absmax unchanged (0.0009765625 all rounds).
// ---------------------------------------------------------------------------
__global__ __launch_bounds__(256) void stdp_gemm(
    const __hip_bfloat16* __restrict__ AT,
    const __hip_bfloat16* __restrict__ BT,
    const float* __restrict__ W,
    float* __restrict__ out)
{
    __shared__ alignas(16) char smem[73728];   // 3 x (A 16384 + B 8192)

    const int tid  = threadIdx.x;
    const int lane = tid & 63;
    const int wv   = tid >> 6;          // wave 0..3
    const int wr   = wv >> 1;           // row-block 0..1 (64 rows each)
    const int wc   = wv & 1;            // col-block 0..1 (32 cols each)
    const int RM   = blockIdx.y * 128;  // q base
    const int CN   = blockIdx.x * 64;   // p base
    const int l15  = lane & 15;
    const int quad = lane >> 4;

    // ---- staging: A 1024 + B 512 chunks over (it, wv, lane) = 6/lane ----
    // chunk c = it*256 + wv*64 + lane; row = c>>3; slot = c&7 = lane&7.
    // row&7 = (lane>>3)&7 (it*32, wv*8 are 0 mod 8).  LDS slot s of row r
    // holds k-chunk s^(r&7) -> global source pre-swizzled.
    const int rS = (wv << 3) + (lane >> 3);          // 0..31 (+32 per it)
    const int kc = (lane & 7) ^ ((lane >> 3) & 7);
    const __hip_bfloat16* sA0 = AT + (size_t)(RM + rS)      * KTOT + kc * 8;
    const __hip_bfloat16* sA1 = AT + (size_t)(RM + rS + 32) * KTOT + kc * 8;
    const __hip_bfloat16* sA2 = AT + (size_t)(RM + rS + 64) * KTOT + kc * 8;
    const __hip_bfloat16* sA3 = AT + (size_t)(RM + rS + 96) * KTOT + kc * 8;
    const __hip_bfloat16* sB0 = BT + (size_t)(CN + rS)      * KTOT + kc * 8;
    const __hip_bfloat16* sB1 = BT + (size_t)(CN + rS + 32) * KTOT + kc * 8;
    const int dS = wv * 1024;           // wave-uniform byte base within section

#define STAGE(BUF, kstep) do {                                   \
        char* bb_ = (BUF);                                       \
        const int ke_ = (kstep) * 64;                            \
        GLOAD_LDS16(sA0 + ke_, bb_ + dS);                        \
        GLOAD_LDS16(sA1 + ke_, bb_ + 4096 + dS);                 \
        GLOAD_LDS16(sA2 + ke_, bb_ + 8192 + dS);                 \
        GLOAD_LDS16(sA3 + ke_, bb_ + 12288 + dS);                \
        GLOAD_LDS16(sB0 + ke_, bb_ + 16384 + dS);                \
        GLOAD_LDS16(sB1 + ke_, bb_ + 20480 + dS);                \
    } while (0)

    // ---- compute: 64x32 per wave = 4x2 accs, 16 MFMA / 12 reads per step ----
    // Baseline-proven fragment pattern: rows by l15, slot by quad (0 conflicts).
    const int mr0 = wr * 64 + l15;
    const int mr1 = mr0 + 16;
    const int mr2 = mr0 + 32;
    const int mr3 = mr0 + 48;
    const int nr0 = wc * 32 + l15;
    const int nr1 = nr0 + 16;

    f32x4 acc[4][2] = {};

#define COMPUTE(BUF) do {                                                         \
        const __hip_bfloat16* Ab_ = (const __hip_bfloat16*)(BUF);                 \
        const __hip_bfloat16* Bb_ = (const __hip_bfloat16*)((BUF) + 16384);       \
        _Pragma("unroll")                                                         \
        for (int kk_ = 0; kk_ < 2; ++kk_) {                                       \
            const int jg_ = kk_ * 4 + quad;                                       \
            bf16x8 b0_ = *(const bf16x8*)(Bb_ + nr0 * 64 + ((jg_ ^ (nr0 & 7)) * 8)); \
            bf16x8 b1_ = *(const bf16x8*)(Bb_ + nr1 * 64 + ((jg_ ^ (nr1 & 7)) * 8)); \
            bf16x8 a0_ = *(const bf16x8*)(Ab_ + mr0 * 64 + ((jg_ ^ (mr0 & 7)) * 8)); \
            bf16x8 a1_ = *(const bf16x8*)(Ab_ + mr1 * 64 + ((jg_ ^ (mr1 & 7)) * 8)); \
            bf16x8 a2_ = *(const bf16x8*)(Ab_ + mr2 * 64 + ((jg_ ^ (mr2 & 7)) * 8)); \
            bf16x8 a3_ = *(const bf16x8*)(Ab_ + mr3 * 64 + ((jg_ ^ (mr3 & 7)) * 8)); \
            acc[0][0] = __builtin_amdgcn_mfma_f32_16x16x32_bf16(a0_, b0_, acc[0][0], 0, 0, 0); \
            acc[0][1] = __builtin_amdgcn_mfma_f32_16x16x32_bf16(a0_, b1_, acc[0][1], 0, 0, 0); \
            acc[1][0] = __builtin_amdgcn_mfma_f32_16x16x32_bf16(a1_, b0_, acc[1][0], 0, 0, 0); \
            acc[1][1] = __builtin_amdgcn_mfma_f32_16x16x32_bf16(a1_, b1_, acc[1][1], 0, 0, 0); \
            acc[2][0] = __builtin_amdgcn_mfma_f32_16x16x32_bf16(a2_, b0_, acc[2][0], 0, 0, 0); \
            acc[2][1] = __builtin_amdgcn_mfma_f32_16x16x32_bf16(a2_, b1_, acc[2][1], 0, 0, 0); \
            acc[3][0] = __builtin_amdgcn_mfma_f32_16x16x32_bf16(a3_, b0_, acc[3][0], 0, 0, 0); \
            acc[3][1] = __builtin_amdgcn_mfma_f32_16x16x32_bf16(a3_, b1_, acc[3][1], 0, 0, 0); \
        }                                                                         \
    } while (0)

#define WAITBAR(N) do {                                          \
        asm volatile("s_waitcnt vmcnt(" #N ")" ::: "memory");    \
        __builtin_amdgcn_s_barrier();                            \
        __builtin_amdgcn_sched_barrier(0);                       \
    } while (0)

    char* B0 = smem;
    char* B1 = smem + 24576;
    char* B2 = smem + 49152;

    // prologue: tiles 0 and 1 in flight; publish tile 0
    STAGE(B0, 0);
    STAGE(B1, 1);
    WAITBAR(6);                          // tile 0 landed (6 = tile 1 in flight)

    // steady state: h = 0..29, buffers cycle (0,1,2); wait always vmcnt(6)
    for (int hb = 0; hb < 30; hb += 3) {
        STAGE(B2, hb + 2); COMPUTE(B0); WAITBAR(6);
        STAGE(B0, hb + 3); COMPUTE(B1); WAITBAR(6);
        STAGE(B1, hb + 4); COMPUTE(B2); WAITBAR(6);
    }
    // h = 30: nothing left to stage; tail drain (the only vmcnt(0))
    COMPUTE(B0);
    WAITBAR(0);                          // tile 31 fully landed
    // h = 31: last tile; no barrier needed after (epilogue touches no LDS)
    COMPUTE(B1);

#undef STAGE
#undef COMPUTE
#undef WAITBAR

    // -------- epilogue: softbound + write, straight from acc --------
    // C/D layout (16x16): local row = i*16 + quad*4 + r, local col = j*16+l15
    #pragma unroll
    for (int i = 0; i < 4; ++i) {
        #pragma unroll
        for (int r = 0; r < 4; ++r) {
            const int q = RM + wr * 64 + i * 16 + quad * 4 + r;
            #pragma unroll
            for (int j = 0; j < 2; ++j) {
                const int p = CN + wc * 32 + j * 16 + l15;
                const float w  = W[(size_t)q * GN + p];
                const float wf = 4.0f * w * (1.0f - w);
                out[(size_t)q * GN + p] = wf * A_SCALE * acc[i][j][r];
            }
        }
    }
}

extern "C" void kernel_launch(void* const* d_in, const int* in_sizes, int n_in,
                              void* d_out, int out_size, void* d_ws, size_t ws_size,
                              hipStream_t stream) {
    const float* W    = (const float*)d_in[0];  // [2048][2048]
    const float* pre  = (const float*)d_in[1];  // [16][128][2048]
    const float* post = (const float*)d_in[2];  // [16][128][2048]
    const int*   dt   = (const int*)d_in[3];
    float* out = (float*)d_out;

    __hip_bfloat16* AT = (__hip_bfloat16*)d_ws;            // 8 MB
    __hip_bfloat16* BT = AT + (size_t)GN * KTOT;           // +8 MB

    trace_kernel<<<dim3(32, 16, 2), 256, 0, stream>>>(pre, post, dt, AT, BT);
    stdp_gemm<<<dim3(32, 16), 256, 0, stream>>>(AT, BT, W, out);
}

// Round 8
// 118.065 us; speedup vs baseline: 1.0151x; 1.0151x over previous
//
#include <hip/hip_runtime.h>
#include <hip/hip_bf16.h>

// STDP via the antisymmetric-kernel identity (verified R6, absmax 9.8e-4):
//   out[q,p] = 4w(1-w) * A_SCALE * sum_{b,t} post_s[b,t,q] * Z[b,t,p]
//   Z = pre_tr - pre_rt;  tr = causal decay scan, rt = anti-causal scan.
//   AT[q][b*128+t] = post_spikes (bf16);  BT[p][b*128+t] = Z (bf16)

typedef __attribute__((ext_vector_type(8))) short bf16x8;
typedef __attribute__((ext_vector_type(4))) float f32x4;

#define GN 2048
#define KTOT 2048
#define A_SCALE (0.01f / 16.0f)
#define FST 68   // fbuf dword stride (16B-aligned float4 rows)
#define ZST 66   // zbuf elem stride (8B-aligned packed writes)

#define GLOAD_LDS16(gp, lp) \
    __builtin_amdgcn_global_load_lds((const __attribute__((address_space(1))) void*)(gp), \
                                     (__attribute__((address_space(3))) void*)(lp), 16, 0, 0)

__device__ __forceinline__ unsigned bf16bits(float x) {
    __hip_bfloat16 h = __float2bfloat16(x);
    return (unsigned)*(unsigned short*)&h;
}

// ---------------------------------------------------------------------------
// Kernel 1: transpose (+ double scan for the pre side), float4 global loads.
// grid (32, 16, 2), block 256 (4 waves). z=0: post -> AT, z=1: pre -> BT.
// zbuf overlays fbuf.  LDS 34816 B -> 4 blocks/CU.  (~12 us, near HBM floor)
// UNCHANGED from the proven baseline.
// ---------------------------------------------------------------------------
__global__ __launch_bounds__(256, 4) void trace_kernel(
    const float* __restrict__ pre,
    const float* __restrict__ post,
    const int* __restrict__ dtp,
    __hip_bfloat16* __restrict__ AT,
    __hip_bfloat16* __restrict__ BT)
{
    __shared__ float fbuf[128 * FST];                    // 34816 B, t-major fp32
    __hip_bfloat16* zbuf = (__hip_bfloat16*)fbuf;        // overlay, t-major bf16

    const int tid = threadIdx.x;
    const int w   = tid >> 6;    // wave 0..3
    const int l   = tid & 63;
    const int nq  = tid & 15;    // float4 group along n
    const int tl  = tid >> 4;    // t-row within a 16-row pass
    const int n0  = blockIdx.x * 64;
    const int b   = blockIdx.y;
    const int a   = blockIdx.z;  // 0: post->AT, 1: pre->BT

    int di = dtp[0];
    float dtf = (di > 0 && di < 1000000) ? (float)di : *(const float*)dtp;
    const float decay = __expf(-dtf / 20.0f);

    if (a == 0) {
        #pragma unroll
        for (int pass = 0; pass < 8; ++pass) {
            const int t = pass * 16 + tl;
            float4 v = *(const float4*)&post[((size_t)b * 128 + t) * GN + n0 + 4 * nq];
            uint2 pk;
            pk.x = bf16bits(v.x) | (bf16bits(v.y) << 16);
            pk.y = bf16bits(v.z) | (bf16bits(v.w) << 16);
            *(uint2*)&zbuf[t * ZST + 4 * nq] = pk;
        }
        __syncthreads();
    } else {
        #pragma unroll
        for (int pass = 0; pass < 8; ++pass) {
            const int t = pass * 16 + tl;
            float4 v = *(const float4*)&pre[((size_t)b * 128 + t) * GN + n0 + 4 * nq];
            *(float4*)&fbuf[t * FST + 4 * nq] = v;
        }
        __syncthreads();

        const int t0 = 32 * w;   // this wave's t segment [t0, t0+32)
        float carry = 0.0f;
        #pragma unroll 8
        for (int t = 1; t < t0; ++t)
            carry = decay * carry + fbuf[t * FST + l];
        float z[32];
        #pragma unroll
        for (int j = 0; j < 32; ++j) {
            const int t = t0 + j;
            if (t >= 1) carry = decay * carry + fbuf[t * FST + l];
            z[j] = carry;                     // tr (t=0 -> 0)
        }
        float bc = 0.0f;
        #pragma unroll 8
        for (int t = 127; t >= t0 + 32; --t)
            bc = decay * bc + fbuf[t * FST + l];
        #pragma unroll
        for (int j = 31; j >= 0; --j) {
            const int t = t0 + j;
            bc = decay * bc + fbuf[t * FST + l];
            if (t >= 1) z[j] -= bc;           // Z = tr - rt   (Z[0] = 0)
        }
        __syncthreads();   // all waves done reading fbuf before zbuf overlay
        #pragma unroll
        for (int j = 0; j < 32; ++j)
            zbuf[(t0 + j) * ZST + l] = __float2bfloat16(z[j]);
        __syncthreads();
    }

    __hip_bfloat16* dst = (a == 0) ? AT : BT;
    #pragma unroll
    for (int j = 0; j < 4; ++j) {
        const int c  = tid + 256 * j;   // 0..1023
        const int n  = c >> 4;          // 0..63
        const int tc = c & 15;          // 8-t chunk
        unsigned int vv[8];
        #pragma unroll
        for (int i = 0; i < 8; ++i)
            vv[i] = *(const unsigned short*)&zbuf[(8 * tc + i) * ZST + n];
        uint4 pk;
        pk.x = vv[0] | (vv[1] << 16);
        pk.y = vv[2] | (vv[3] << 16);
        pk.z = vv[4] | (vv[5] << 16);
        pk.w = vv[6] | (vv[7] << 16);
        *(uint4*)(dst + (size_t)(n0 + n) * KTOT + b * 128 + tc * 8) = pk;
    }
}

// ---------------------------------------------------------------------------
// Kernel 2: out = 4w(1-w)*A_SCALE * (AT * BT^T).
// R8 = R6's proven pipeline/occupancy/fragment pattern at a 2x BIGGER BLOCK
// TILE.  Post-mortem: R6 (117.7, best) is LDS-pipe bound (reads 1536 +
// writes 384 cyc of the ~2325 cyc CU-step); R7 proved savings don't cash
// below 4 waves/SIMD; R5 proved 32-row reads conflict.  This config keeps
// ALL proven choices -- 16 waves/CU (4/SIMD), 32x32 wave tiles, 16-row/
// quad-slot reads (0 conflicts), 8-slot XOR swizzle on 128B rows, 3-buffer
// counted-vmcnt pipeline -- and changes only the aggregation: ONE 1024-
// thread block of 128x128 per CU instead of two 512-thread 128x64 blocks.
//   * staging-writes per CU-step: 48 KB -> 32 KB (-33%)
//   * L2 staging traffic: 786 MB -> 262 MB (-66%)
//   * LDS read count/CU-step unchanged (128 b128)
//   * 2 gload_lds per lane per tile -> steady-state wait vmcnt(2)
//     (tile h+2's 2 loads in flight, tile h+1 landed; R4/R6 induction)
// LDS 3 x 32 KB = 96 KB -> guaranteed 1 block/CU; grid 16x16 = 256 = 1/CU.
// K-order: kk ascending -> absmax unchanged (0.0009765625 all rounds).
// ---------------------------------------------------------------------------
__global__ __launch_bounds__(1024) void stdp_gemm(
    const __hip_bfloat16* __restrict__ AT,
    const __hip_bfloat16* __restrict__ BT,
    const float* __restrict__ W,
    float* __restrict__ out)
{
    __shared__ alignas(16) char smem[98304];   // 3 x (A 16384 + B 16384)

    const int tid  = threadIdx.x;
    const int lane = tid & 63;
    const int wv16 = tid >> 6;          // wave 0..15
    const int wr   = wv16 >> 2;         // row-block 0..3 (32 rows each)
    const int wc   = wv16 & 3;          // col-block 0..3 (32 cols each)
    const int RM   = blockIdx.y * 128;  // q base
    const int CN   = blockIdx.x * 128;  // p base
    const int l15  = lane & 15;
    const int quad = lane >> 4;

    // ---- staging: A 1024 chunks + B 1024 chunks over (wv16, lane) ----
    // chunk c = wv16*64 + lane (0..1023); row = c>>3 (0..127); slot = c&7 =
    // lane&7; row&7 = (lane>>3)&7 (wv16*8 is 0 mod 8).  LDS slot s of row r
    // holds k-chunk s^(r&7) -> global source pre-swizzled (proven R4/R6/R7).
    const int rS = (wv16 << 3) + (lane >> 3);        // 0..127
    const int kc = (lane & 7) ^ ((lane >> 3) & 7);
    const __hip_bfloat16* sA = AT + (size_t)(RM + rS) * KTOT + kc * 8;
    const __hip_bfloat16* sB = BT + (size_t)(CN + rS) * KTOT + kc * 8;
    const int dS = wv16 * 1024;         // wave-uniform byte base (chunk*16)

#define STAGE(BUF, kstep) do {                                   \
        char* bb_ = (BUF);                                       \
        const int ke_ = (kstep) * 64;                            \
        GLOAD_LDS16(sA + ke_, bb_ + dS);                         \
        GLOAD_LDS16(sB + ke_, bb_ + 16384 + dS);                 \
    } while (0)

    // ---- compute: 32x32 per wave via 16x16x32, 2x2 accs, 8 MFMA / BK=64 ----
    // Proven conflict-free pattern: rows by l15 (16 rows/read), slot by quad.
    const int mr0 = wr * 32 + l15;
    const int mr1 = mr0 + 16;
    const int nr0 = wc * 32 + l15;
    const int nr1 = nr0 + 16;

    f32x4 acc00 = {}, acc01 = {}, acc10 = {}, acc11 = {};

#define COMPUTE(BUF) do {                                                         \
        const __hip_bfloat16* Ab_ = (const __hip_bfloat16*)(BUF);                 \
        const __hip_bfloat16* Bb_ = (const __hip_bfloat16*)((BUF) + 16384);       \
        _Pragma("unroll")                                                         \
        for (int kk_ = 0; kk_ < 2; ++kk_) {                                       \
            const int jg_ = kk_ * 4 + quad;                                       \
            bf16x8 a0_ = *(const bf16x8*)(Ab_ + mr0 * 64 + ((jg_ ^ (mr0 & 7)) * 8)); \
            bf16x8 a1_ = *(const bf16x8*)(Ab_ + mr1 * 64 + ((jg_ ^ (mr1 & 7)) * 8)); \
            bf16x8 b0_ = *(const bf16x8*)(Bb_ + nr0 * 64 + ((jg_ ^ (nr0 & 7)) * 8)); \
            bf16x8 b1_ = *(const bf16x8*)(Bb_ + nr1 * 64 + ((jg_ ^ (nr1 & 7)) * 8)); \
            acc00 = __builtin_amdgcn_mfma_f32_16x16x32_bf16(a0_, b0_, acc00, 0, 0, 0); \
            acc01 = __builtin_amdgcn_mfma_f32_16x16x32_bf16(a0_, b1_, acc01, 0, 0, 0); \
            acc10 = __builtin_amdgcn_mfma_f32_16x16x32_bf16(a1_, b0_, acc10, 0, 0, 0); \
            acc11 = __builtin_amdgcn_mfma_f32_16x16x32_bf16(a1_, b1_, acc11, 0, 0, 0); \
        }                                                                         \
    } while (0)

#define WAITBAR(N) do {                                          \
        asm volatile("s_waitcnt vmcnt(" #N ")" ::: "memory");    \
        __builtin_amdgcn_s_barrier();                            \
        __builtin_amdgcn_sched_barrier(0);                       \
    } while (0)

    char* B0 = smem;
    char* B1 = smem + 32768;
    char* B2 = smem + 65536;

    // prologue: tiles 0 and 1 in flight; publish tile 0
    STAGE(B0, 0);
    STAGE(B1, 1);
    WAITBAR(2);                          // tile 0 landed (2 = tile 1 in flight)

    // steady state: h = 0..29, buffers cycle (0,1,2); wait always vmcnt(2)
    for (int hb = 0; hb < 30; hb += 3) {
        STAGE(B2, hb + 2); COMPUTE(B0); WAITBAR(2);
        STAGE(B0, hb + 3); COMPUTE(B1); WAITBAR(2);
        STAGE(B1, hb + 4); COMPUTE(B2); WAITBAR(2);
    }
    // h = 30: nothing left to stage; tail drain (the only vmcnt(0))
    COMPUTE(B0);
    WAITBAR(0);                          // tile 31 fully landed
    // h = 31: last tile; no barrier needed after (epilogue touches no LDS)
    COMPUTE(B1);

#undef STAGE
#undef COMPUTE
#undef WAITBAR

    // -------- epilogue: softbound + write, straight from acc --------
    // C/D layout (16x16): local row = i*16 + quad*4 + r, local col = j*16+l15
    #pragma unroll
    for (int i = 0; i < 2; ++i) {
        #pragma unroll
        for (int j = 0; j < 2; ++j) {
            const f32x4 a = (i == 0) ? (j == 0 ? acc00 : acc01)
                                     : (j == 0 ? acc10 : acc11);
            const int p = CN + wc * 32 + j * 16 + l15;
            #pragma unroll
            for (int r = 0; r < 4; ++r) {
                const int q = RM + wr * 32 + i * 16 + quad * 4 + r;
                const float w  = W[(size_t)q * GN + p];
                const float wf = 4.0f * w * (1.0f - w);
                out[(size_t)q * GN + p] = wf * A_SCALE * a[r];
            }
        }
    }
}

extern "C" void kernel_launch(void* const* d_in, const int* in_sizes, int n_in,
                              void* d_out, int out_size, void* d_ws, size_t ws_size,
                              hipStream_t stream) {
    const float* W    = (const float*)d_in[0];  // [2048][2048]
    const float* pre  = (const float*)d_in[1];  // [16][128][2048]
    const float* post = (const float*)d_in[2];  // [16][128][2048]
    const int*   dt   = (const int*)d_in[3];
    float* out = (float*)d_out;

    __hip_bfloat16* AT = (__hip_bfloat16*)d_ws;            // 8 MB
    __hip_bfloat16* BT = AT + (size_t)GN * KTOT;           // +8 MB

    trace_kernel<<<dim3(32, 16, 2), 256, 0, stream>>>(pre, post, dt, AT, BT);
    stdp_gemm<<<dim3(16, 16), 1024, 0, stream>>>(AT, BT, W, out);
}

// Round 9
// 117.520 us; speedup vs baseline: 1.0199x; 1.0046x over previous
//
#include <hip/hip_runtime.h>
#include <hip/hip_bf16.h>

// STDP via the antisymmetric-kernel identity (verified R6, absmax 9.8e-4):
//   out[q,p] = 4w(1-w) * A_SCALE * sum_{b,t} post_s[b,t,q] * Z[b,t,p]
//   Z = pre_tr - pre_rt;  tr = causal decay scan, rt = anti-causal scan.
//   AT[q][b*128+t] = post_spikes (bf16);  BT[p][b*128+t] = Z (bf16)

typedef __attribute__((ext_vector_type(8))) short bf16x8;
typedef __attribute__((ext_vector_type(4))) float f32x4;

#define GN 2048
#define KTOT 2048
#define A_SCALE (0.01f / 16.0f)
#define FST 68   // fbuf dword stride (16B-aligned float4 rows)
#define ZST 66   // zbuf elem stride (8B-aligned packed writes)

#define GLOAD_LDS16(gp, lp) \
    __builtin_amdgcn_global_load_lds((const __attribute__((address_space(1))) void*)(gp), \
                                     (__attribute__((address_space(3))) void*)(lp), 16, 0, 0)

__device__ __forceinline__ unsigned bf16bits(float x) {
    __hip_bfloat16 h = __float2bfloat16(x);
    return (unsigned)*(unsigned short*)&h;
}

// ---------------------------------------------------------------------------
// Kernel 1: transpose (+ double scan for the pre side), float4 global loads.
// grid (32, 16, 2), block 256 (4 waves). z=0: post -> AT, z=1: pre -> BT.
// zbuf overlays fbuf.  LDS 34816 B -> 4 blocks/CU.  (~12 us, near HBM floor)
// UNCHANGED from the proven baseline.
// ---------------------------------------------------------------------------
__global__ __launch_bounds__(256, 4) void trace_kernel(
    const float* __restrict__ pre,
    const float* __restrict__ post,
    const int* __restrict__ dtp,
    __hip_bfloat16* __restrict__ AT,
    __hip_bfloat16* __restrict__ BT)
{
    __shared__ float fbuf[128 * FST];                    // 34816 B, t-major fp32
    __hip_bfloat16* zbuf = (__hip_bfloat16*)fbuf;        // overlay, t-major bf16

    const int tid = threadIdx.x;
    const int w   = tid >> 6;    // wave 0..3
    const int l   = tid & 63;
    const int nq  = tid & 15;    // float4 group along n
    const int tl  = tid >> 4;    // t-row within a 16-row pass
    const int n0  = blockIdx.x * 64;
    const int b   = blockIdx.y;
    const int a   = blockIdx.z;  // 0: post->AT, 1: pre->BT

    int di = dtp[0];
    float dtf = (di > 0 && di < 1000000) ? (float)di : *(const float*)dtp;
    const float decay = __expf(-dtf / 20.0f);

    if (a == 0) {
        #pragma unroll
        for (int pass = 0; pass < 8; ++pass) {
            const int t = pass * 16 + tl;
            float4 v = *(const float4*)&post[((size_t)b * 128 + t) * GN + n0 + 4 * nq];
            uint2 pk;
            pk.x = bf16bits(v.x) | (bf16bits(v.y) << 16);
            pk.y = bf16bits(v.z) | (bf16bits(v.w) << 16);
            *(uint2*)&zbuf[t * ZST + 4 * nq] = pk;
        }
        __syncthreads();
    } else {
        #pragma unroll
        for (int pass = 0; pass < 8; ++pass) {
            const int t = pass * 16 + tl;
            float4 v = *(const float4*)&pre[((size_t)b * 128 + t) * GN + n0 + 4 * nq];
            *(float4*)&fbuf[t * FST + 4 * nq] = v;
        }
        __syncthreads();

        const int t0 = 32 * w;   // this wave's t segment [t0, t0+32)
        float carry = 0.0f;
        #pragma unroll 8
        for (int t = 1; t < t0; ++t)
            carry = decay * carry + fbuf[t * FST + l];
        float z[32];
        #pragma unroll
        for (int j = 0; j < 32; ++j) {
            const int t = t0 + j;
            if (t >= 1) carry = decay * carry + fbuf[t * FST + l];
            z[j] = carry;                     // tr (t=0 -> 0)
        }
        float bc = 0.0f;
        #pragma unroll 8
        for (int t = 127; t >= t0 + 32; --t)
            bc = decay * bc + fbuf[t * FST + l];
        #pragma unroll
        for (int j = 31; j >= 0; --j) {
            const int t = t0 + j;
            bc = decay * bc + fbuf[t * FST + l];
            if (t >= 1) z[j] -= bc;           // Z = tr - rt   (Z[0] = 0)
        }
        __syncthreads();   // all waves done reading fbuf before zbuf overlay
        #pragma unroll
        for (int j = 0; j < 32; ++j)
            zbuf[(t0 + j) * ZST + l] = __float2bfloat16(z[j]);
        __syncthreads();
    }

    __hip_bfloat16* dst = (a == 0) ? AT : BT;
    #pragma unroll
    for (int j = 0; j < 4; ++j) {
        const int c  = tid + 256 * j;   // 0..1023
        const int n  = c >> 4;          // 0..63
        const int tc = c & 15;          // 8-t chunk
        unsigned int vv[8];
        #pragma unroll
        for (int i = 0; i < 8; ++i)
            vv[i] = *(const unsigned short*)&zbuf[(8 * tc + i) * ZST + n];
        uint4 pk;
        pk.x = vv[0] | (vv[1] << 16);
        pk.y = vv[2] | (vv[3] << 16);
        pk.z = vv[4] | (vv[5] << 16);
        pk.w = vv[6] | (vv[7] << 16);
        *(uint4*)(dst + (size_t)(n0 + n) * KTOT + b * 128 + tc * 8) = pk;
    }
}

// ---------------------------------------------------------------------------
// Kernel 2: out = 4w(1-w)*A_SCALE * (AT * BT^T).
// R9 = R6 champion (117.7us) + two scheduling-only changes:
//   (1) T5: s_setprio(1) around the MFMA cluster.  R6 has two independent
//       blocks/CU with unsynchronized stage/compute phases (m97-regime
//       cross-cover) -> genuine wave-role diversity, the regime where T5
//       measured +21-39% (m218b/m224) vs null on lockstep (m190).
//   (2) All 8 fragment ds_reads hoisted ahead of all 8 MFMAs per step
//       (was read-4/mfma-4 x2) -> more outstanding lgkm, kk=0 MFMAs cover
//       kk=1's read latency.  VGPR ~90 < 128, 4 waves/SIMD preserved.
// Everything else byte-identical to R6: 512 blocks x 128x64 tile, 8 waves
// of 32x32 via 16x16x32 (16-row/quad-slot reads, 0 conflicts), 3 x 24KB
// LDS buffers (2 blocks/CU, 16 waves/CU), counted vmcnt(3) pipeline with
// drain-0 only at the tail, 8-slot XOR swizzle on 128B rows, uniform
// barriers + sched_barrier(0) (rule #18).
// K-order: kk ascending -> absmax unchanged (0.0009765625 all rounds).
// ---------------------------------------------------------------------------
__global__ __launch_bounds__(512, 4) void stdp_gemm(
    const __hip_bfloat16* __restrict__ AT,
    const __hip_bfloat16* __restrict__ BT,
    const float* __restrict__ W,
    float* __restrict__ out)
{
    __shared__ alignas(16) char smem[73728];   // 3 x (A 16384 + B 8192)

    const int tid  = threadIdx.x;
    const int lane = tid & 63;
    const int wv8  = tid >> 6;          // wave 0..7
    const int wr   = wv8 >> 1;          // row-block 0..3  (32 rows each)
    const int wc   = wv8 & 1;           // col-block 0..1  (32 cols each)
    const int RM   = blockIdx.y * 128;  // q base
    const int CN   = blockIdx.x * 64;   // p base
    const int l15  = lane & 15;
    const int quad = lane >> 4;

    // ---- staging assignment: 3 gload_lds per wave per tile (R6-verbatim) ----
    // A: 128 rows x 8 chunks(16B) = 1024 chunks; B: 64 rows x 8 = 512 chunks.
    // LDS slot (c&7) of row r holds k-chunk (c&7)^(r&7) (source pre-swizzled).
    const int cS   = wv8 * 64 + lane;   // 0..511
    const int rS   = cS >> 3;           // 0..63
    const int sS   = cS & 7;
    const int kc0  = sS ^ (rS & 7);
    const int kc1  = sS ^ ((rS + 64) & 7);
    const __hip_bfloat16* srcA0 = AT + (size_t)(RM + rS)      * KTOT + kc0 * 8;
    const __hip_bfloat16* srcA1 = AT + (size_t)(RM + rS + 64) * KTOT + kc1 * 8;
    const __hip_bfloat16* srcB  = BT + (size_t)(CN + rS)      * KTOT + kc0 * 8;
    const int dS = wv8 * 1024;          // (wv8*64 chunks)*16B, wave-uniform base

#define STAGE(BUF, kstep) do {                                   \
        char* bb_ = (BUF);                                       \
        const int ke_ = (kstep) * 64;                            \
        GLOAD_LDS16(srcA0 + ke_, bb_ + dS);                      \
        GLOAD_LDS16(srcA1 + ke_, bb_ + 8192 + dS);               \
        GLOAD_LDS16(srcB  + ke_, bb_ + 16384 + dS);              \
    } while (0)

    // ---- compute: 32x32 per wave via 16x16x32, 2x2 accs, 8 MFMA / BK=64 ----
    // Fragment rows by l15 (16 distinct rows/read), slot by quad -> the
    // measured-conflict-free pattern.  jg = kk*4 + quad in {quad, 4+quad}.
    const int mr0 = wr * 32 + l15;      // A rows (i=0; i=1 adds 16)
    const int mr1 = mr0 + 16;
    const int nr0 = wc * 32 + l15;      // B rows
    const int nr1 = nr0 + 16;

    f32x4 acc00 = {}, acc01 = {}, acc10 = {}, acc11 = {};

#define COMPUTE(BUF) do {                                                         \
        const __hip_bfloat16* Ab_ = (const __hip_bfloat16*)(BUF);                 \
        const __hip_bfloat16* Bb_ = (const __hip_bfloat16*)((BUF) + 16384);       \
        bf16x8 a0k0 = *(const bf16x8*)(Ab_ + mr0 * 64 + ((quad ^ (mr0 & 7)) * 8));       \
        bf16x8 a1k0 = *(const bf16x8*)(Ab_ + mr1 * 64 + ((quad ^ (mr1 & 7)) * 8));       \
        bf16x8 b0k0 = *(const bf16x8*)(Bb_ + nr0 * 64 + ((quad ^ (nr0 & 7)) * 8));       \
        bf16x8 b1k0 = *(const bf16x8*)(Bb_ + nr1 * 64 + ((quad ^ (nr1 & 7)) * 8));       \
        bf16x8 a0k1 = *(const bf16x8*)(Ab_ + mr0 * 64 + (((4 + quad) ^ (mr0 & 7)) * 8)); \
        bf16x8 a1k1 = *(const bf16x8*)(Ab_ + mr1 * 64 + (((4 + quad) ^ (mr1 & 7)) * 8)); \
        bf16x8 b0k1 = *(const bf16x8*)(Bb_ + nr0 * 64 + (((4 + quad) ^ (nr0 & 7)) * 8)); \
        bf16x8 b1k1 = *(const bf16x8*)(Bb_ + nr1 * 64 + (((4 + quad) ^ (nr1 & 7)) * 8)); \
        __builtin_amdgcn_s_setprio(1);                                            \
        acc00 = __builtin_amdgcn_mfma_f32_16x16x32_bf16(a0k0, b0k0, acc00, 0, 0, 0); \
        acc01 = __builtin_amdgcn_mfma_f32_16x16x32_bf16(a0k0, b1k0, acc01, 0, 0, 0); \
        acc10 = __builtin_amdgcn_mfma_f32_16x16x32_bf16(a1k0, b0k0, acc10, 0, 0, 0); \
        acc11 = __builtin_amdgcn_mfma_f32_16x16x32_bf16(a1k0, b1k0, acc11, 0, 0, 0); \
        acc00 = __builtin_amdgcn_mfma_f32_16x16x32_bf16(a0k1, b0k1, acc00, 0, 0, 0); \
        acc01 = __builtin_amdgcn_mfma_f32_16x16x32_bf16(a0k1, b1k1, acc01, 0, 0, 0); \
        acc10 = __builtin_amdgcn_mfma_f32_16x16x32_bf16(a1k1, b0k1, acc10, 0, 0, 0); \
        acc11 = __builtin_amdgcn_mfma_f32_16x16x32_bf16(a1k1, b1k1, acc11, 0, 0, 0); \
        __builtin_amdgcn_s_setprio(0);                                            \
    } while (0)

#define WAITBAR(N) do {                                          \
        asm volatile("s_waitcnt vmcnt(" #N ")" ::: "memory");    \
        __builtin_amdgcn_s_barrier();                            \
        __builtin_amdgcn_sched_barrier(0);                       \
    } while (0)

    char* B0 = smem;
    char* B1 = smem + 24576;
    char* B2 = smem + 49152;

    // prologue: tiles 0 and 1 in flight; publish tile 0
    STAGE(B0, 0);
    STAGE(B1, 1);
    WAITBAR(3);                          // tile 0 landed (3 = tile 1 in flight)

    // steady state: h = 0..29, buffers cycle (0,1,2); wait always vmcnt(3)
    for (int hb = 0; hb < 30; hb += 3) {
        STAGE(B2, hb + 2); COMPUTE(B0); WAITBAR(3);
        STAGE(B0, hb + 3); COMPUTE(B1); WAITBAR(3);
        STAGE(B1, hb + 4); COMPUTE(B2); WAITBAR(3);
    }
    // h = 30: nothing left to stage; tail drain (the only vmcnt(0))
    COMPUTE(B0);
    WAITBAR(0);                          // tile 31 fully landed
    // h = 31: last tile; no barrier needed after (epilogue touches no LDS)
    COMPUTE(B1);

#undef STAGE
#undef COMPUTE
#undef WAITBAR

    // -------- epilogue: softbound + write, straight from acc --------
    // C/D layout (16x16): local row = i*16 + quad*4 + r, local col = j*16+l15
    #pragma unroll
    for (int i = 0; i < 2; ++i) {
        #pragma unroll
        for (int j = 0; j < 2; ++j) {
            const f32x4 a = (i == 0) ? (j == 0 ? acc00 : acc01)
                                     : (j == 0 ? acc10 : acc11);
            const int p = CN + wc * 32 + j * 16 + l15;
            #pragma unroll
            for (int r = 0; r < 4; ++r) {
                const int q = RM + wr * 32 + i * 16 + quad * 4 + r;
                const float w  = W[(size_t)q * GN + p];
                const float wf = 4.0f * w * (1.0f - w);
                out[(size_t)q * GN + p] = wf * A_SCALE * a[r];
            }
        }
    }
}

extern "C" void kernel_launch(void* const* d_in, const int* in_sizes, int n_in,
                              void* d_out, int out_size, void* d_ws, size_t ws_size,
                              hipStream_t stream) {
    const float* W    = (const float*)d_in[0];  // [2048][2048]
    const float* pre  = (const float*)d_in[1];  // [16][128][2048]
    const float* post = (const float*)d_in[2];  // [16][128][2048]
    const int*   dt   = (const int*)d_in[3];
    float* out = (float*)d_out;

    __hip_bfloat16* AT = (__hip_bfloat16*)d_ws;            // 8 MB
    __hip_bfloat16* BT = AT + (size_t)GN * KTOT;           // +8 MB

    trace_kernel<<<dim3(32, 16, 2), 256, 0, stream>>>(pre, post, dt, AT, BT);
    stdp_gemm<<<dim3(32, 16), 512, 0, stream>>>(AT, BT, W, out);
}